// Round 2
// baseline (310.297 us; speedup 1.0000x reference)
//
#include <hip/hip_runtime.h>
#include <hip/hip_bf16.h>

#define EMBED 768
#define NHEADS 8
#define HDIM 96
#define SEQ 2048
#define BATCH 4
#define NTOK (BATCH*SEQ)   // 8192
#define QKVN (3*EMBED)     // 2304

// 1/sqrt(96) * log2(e): softmax computed in exp2 domain
#define QSCALE 0.14724444f

typedef __attribute__((ext_vector_type(4))) float f32x4;
typedef __attribute__((ext_vector_type(8))) __bf16 bf16x8;

__device__ __forceinline__ unsigned short f2bf(float f) {
  union { float f; unsigned int u; } c; c.f = f;
  unsigned int u = c.u;
  return (unsigned short)((u + 0x7FFFu + ((u >> 16) & 1u)) >> 16);
}

__device__ __forceinline__ void gload_lds16(const void* g, void* l) {
  __builtin_amdgcn_global_load_lds(
      (const __attribute__((address_space(1))) unsigned int*)g,
      (__attribute__((address_space(3))) unsigned int*)l, 16, 0, 0);
}

// ---------------- cast x -> bf16 ----------------
__global__ __launch_bounds__(256) void cast_x_kernel(const float4* __restrict__ in,
                                                     ushort4* __restrict__ out, int n4) {
  int i = blockIdx.x * 256 + threadIdx.x;
  if (i >= n4) return;
  float4 v = in[i];
  out[i] = make_ushort4(f2bf(v.x), f2bf(v.y), f2bf(v.z), f2bf(v.w));
}

// ---------------- transpose+cast W [R][C] f32 -> [C][R] bf16 ----------------
__global__ __launch_bounds__(256) void transpose_cast_kernel(const float* __restrict__ in,
                                                             unsigned short* __restrict__ out,
                                                             int R, int C) {
  __shared__ float t[32][33];
  int c0 = blockIdx.x * 32, r0 = blockIdx.y * 32;
  int tx = threadIdx.x & 31, ty = threadIdx.x >> 5;  // 32 x 8
  #pragma unroll
  for (int i = 0; i < 32; i += 8)
    t[ty + i][tx] = in[(size_t)(r0 + ty + i) * C + c0 + tx];
  __syncthreads();
  #pragma unroll
  for (int i = 0; i < 32; i += 8)
    out[(size_t)(c0 + ty + i) * R + r0 + tx] = f2bf(t[tx][ty + i]);
}

// ---------------- GEMM: A[M][K] bf16 x B[N][K] bf16 (B pre-transposed) ----------------
template <int MODE>
__global__ __launch_bounds__(256) void gemm_kernel(
    const unsigned short* __restrict__ A, const unsigned short* __restrict__ B,
    const float* __restrict__ bias, int K,
    unsigned short* __restrict__ Qo, unsigned short* __restrict__ Ko,
    unsigned short* __restrict__ Vt, float* __restrict__ out) {
  __shared__ unsigned short As[128][32];
  __shared__ unsigned short Bs[128][32];
  const int tid = threadIdx.x;
  const int lane = tid & 63, wid = tid >> 6;
  const int wr = wid >> 1, wc = wid & 1;
  const int l15 = lane & 15, l16 = lane >> 4;
  const int m0 = blockIdx.y * 128, n0 = blockIdx.x * 128;

  f32x4 acc[4][4] = {};

  for (int k0 = 0; k0 < K; k0 += 32) {
    __syncthreads();
    #pragma unroll
    for (int i = 0; i < 2; i++) {
      int chunk = i * 256 + tid;
      gload_lds16(A + (size_t)(m0 + (chunk >> 2)) * K + k0 + (chunk & 3) * 8,
                  (char*)As + (i * 256 + wid * 64) * 16);
      gload_lds16(B + (size_t)(n0 + (chunk >> 2)) * K + k0 + (chunk & 3) * 8,
                  (char*)Bs + (i * 256 + wid * 64) * 16);
    }
    __syncthreads();

    bf16x8 af[4], bfr[4];
    #pragma unroll
    for (int mi = 0; mi < 4; mi++)
      af[mi] = *(const bf16x8*)&As[wr * 64 + mi * 16 + l15][l16 * 8];
    #pragma unroll
    for (int ni = 0; ni < 4; ni++)
      bfr[ni] = *(const bf16x8*)&Bs[wc * 64 + ni * 16 + l15][l16 * 8];
    #pragma unroll
    for (int mi = 0; mi < 4; mi++)
      #pragma unroll
      for (int ni = 0; ni < 4; ni++)
        acc[mi][ni] = __builtin_amdgcn_mfma_f32_16x16x32_bf16(af[mi], bfr[ni], acc[mi][ni], 0, 0, 0);
  }

  if (MODE == 0) {
    #pragma unroll
    for (int mi = 0; mi < 4; mi++) {
      #pragma unroll
      for (int ni = 0; ni < 4; ni++) {
        int col = n0 + wc * 64 + ni * 16 + l15;   // 0..2303
        int h = col / 288;
        int rem = col - h * 288;
        int d = rem / 3;
        int which = rem - d * 3;
        float bb = bias[col];
        #pragma unroll
        for (int j = 0; j < 4; j++) {
          int row = m0 + wr * 64 + mi * 16 + l16 * 4 + j;  // token 0..8191
          int bi = row >> 11, nn = row & 2047;
          float v = acc[mi][ni][j] + bb;
          size_t bh = (size_t)(bi * NHEADS + h);
          if (which == 0)      Qo[(bh * SEQ + nn) * HDIM + d] = f2bf(v * QSCALE);
          else if (which == 1) Ko[(bh * SEQ + nn) * HDIM + d] = f2bf(v);
          else                 Vt[(bh * HDIM + d) * SEQ + nn] = f2bf(v);
        }
      }
    }
  } else {
    #pragma unroll
    for (int mi = 0; mi < 4; mi++) {
      #pragma unroll
      for (int ni = 0; ni < 4; ni++) {
        int col = n0 + wc * 64 + ni * 16 + l15;
        float bb = bias[col];
        #pragma unroll
        for (int j = 0; j < 4; j++) {
          int row = m0 + wr * 64 + mi * 16 + l16 * 4 + j;
          out[(size_t)row * EMBED + col] = acc[mi][ni][j] + bb;
        }
      }
    }
  }
}

// ---------------- flash attention ----------------
// Q [B*H][N][96] bf16 (pre-scaled by 1/sqrt(96)*log2e), K same layout,
// Vt [B*H][96][N] bf16. Out: attn [B][N][H*96] bf16.
// Softmax in exp2 domain. KVBLK=128, QBLK=128 (4 waves x 32 rows).
__global__ __launch_bounds__(256, 2) void attn_kernel(
    const unsigned short* __restrict__ Q, const unsigned short* __restrict__ Kd,
    const unsigned short* __restrict__ Vt, unsigned short* __restrict__ Oa) {
  __shared__ unsigned short Ks[128 * 96];       // 24 KB row-major [128][96]
  __shared__ unsigned short Vs[96 * 128];       // 24 KB [96][128], rows XOR-swizzled
  __shared__ unsigned short Ps[4 * 32 * 128];   // 32 KB per-wave [32][128], XOR-swizzled

  const int tid = threadIdx.x, lane = tid & 63, wid = tid >> 6;
  const int l15 = lane & 15, l16 = lane >> 4;
  // XCD swizzle: 512 blocks, 8 XCDs -> each XCD owns 4 consecutive (b,h)
  const int bid = blockIdx.x;
  const int swz = (bid & 7) * 64 + (bid >> 3);
  const int qb = swz & 15, bh = swz >> 4;
  const int bi = bh >> 3, h = bh & 7;
  const int q0 = qb * 128;

  const unsigned short* Qg = Q + ((size_t)bh * SEQ + q0) * HDIM;
  const unsigned short* Kg = Kd + (size_t)bh * SEQ * HDIM;
  const unsigned short* Vg = Vt + (size_t)bh * HDIM * SEQ;

  // Q fragments hoisted to registers (loop-invariant, wave-private rows)
  bf16x8 qf[2][3];
  #pragma unroll
  for (int mi = 0; mi < 2; mi++)
    #pragma unroll
    for (int ks = 0; ks < 3; ks++)
      qf[mi][ks] = *(const bf16x8*)(Qg + (size_t)(wid * 32 + mi * 16 + l15) * HDIM + ks * 32 + l16 * 8);

  f32x4 oacc[2][6] = {};
  float mrow[2][4], lrow[2][4];
  #pragma unroll
  for (int mi = 0; mi < 2; mi++)
    #pragma unroll
    for (int j = 0; j < 4; j++) { mrow[mi][j] = -__builtin_inff(); lrow[mi][j] = 0.f; }

  char* PsW = (char*)Ps + wid * 8192;

  for (int kb = 0; kb < SEQ / 128; kb++) {
    const int k0 = kb * 128;
    __syncthreads();  // previous iteration's LDS readers done
    // stage K tile: row-major [128][96], linear (balanced banks: stride 48 dw)
    #pragma unroll
    for (int i = 0; i < 6; i++) {
      int idx = i * 256 + tid;
      gload_lds16(Kg + (size_t)k0 * HDIM + idx * 8, (char*)Ks + (i * 256 + wid * 64) * 16);
    }
    // stage V^T tile [96][128] with XOR swizzle (d&7)<<4: pre-swizzled source
    #pragma unroll
    for (int i = 0; i < 6; i++) {
      int idx = i * 256 + tid;
      int d = idx >> 4, slot = idx & 15;
      gload_lds16(Vg + (size_t)d * SEQ + k0 + ((slot ^ (d & 7)) << 3),
                  (char*)Vs + (i * 256 + wid * 64) * 16);
    }
    __syncthreads();

    // ---- S = Q K^T (rows wid*32+mi*16+l16*4+j, cols ni*16+l15) ----
    f32x4 sacc[2][8] = {};
    #pragma unroll
    for (int ks = 0; ks < 3; ks++) {
      bf16x8 bk[8];
      #pragma unroll
      for (int ni = 0; ni < 8; ni++)
        bk[ni] = *(const bf16x8*)((const char*)Ks + (ni * 16 + l15) * 192 + ks * 64 + l16 * 16);
      __builtin_amdgcn_s_setprio(1);
      #pragma unroll
      for (int mi = 0; mi < 2; mi++)
        #pragma unroll
        for (int ni = 0; ni < 8; ni++)
          sacc[mi][ni] = __builtin_amdgcn_mfma_f32_16x16x32_bf16(qf[mi][ks], bk[ni], sacc[mi][ni], 0, 0, 0);
      __builtin_amdgcn_s_setprio(0);
    }

    // ---- tile row-maxima ----
    float tmax[2][4];
    float g = -3.4e38f;
    #pragma unroll
    for (int mi = 0; mi < 2; mi++) {
      #pragma unroll
      for (int j = 0; j < 4; j++) {
        float v = fmaxf(fmaxf(fmaxf(sacc[mi][0][j], sacc[mi][1][j]),
                              fmaxf(sacc[mi][2][j], sacc[mi][3][j])),
                        fmaxf(fmaxf(sacc[mi][4][j], sacc[mi][5][j]),
                              fmaxf(sacc[mi][6][j], sacc[mi][7][j])));
        v = fmaxf(v, __shfl_xor(v, 1));
        v = fmaxf(v, __shfl_xor(v, 2));
        v = fmaxf(v, __shfl_xor(v, 4));
        v = fmaxf(v, __shfl_xor(v, 8));
        tmax[mi][j] = v;
        g = fmaxf(g, v - mrow[mi][j]);
      }
    }
    // T13 defer-max: THR = 8*log2e (exp2 domain)
    if (!__all(g <= 11.54f)) {
      #pragma unroll
      for (int mi = 0; mi < 2; mi++) {
        #pragma unroll
        for (int j = 0; j < 4; j++) {
          float mnew = fmaxf(mrow[mi][j], tmax[mi][j]);
          float alpha = __builtin_amdgcn_exp2f(mrow[mi][j] - mnew);
          mrow[mi][j] = mnew;
          lrow[mi][j] *= alpha;
          #pragma unroll
          for (int ni = 0; ni < 6; ni++) {
            oacc[mi][ni][0] *= alpha; oacc[mi][ni][1] *= alpha;
            oacc[mi][ni][2] *= alpha; oacc[mi][ni][3] *= alpha;
          }
        }
      }
    }

    // ---- P = exp2(S - m); write to swizzled per-wave LDS; accumulate l ----
    #pragma unroll
    for (int mi = 0; mi < 2; mi++) {
      #pragma unroll
      for (int j = 0; j < 4; j++) {
        const int prow = mi * 16 + l16 * 4 + j;
        char* pb = PsW + prow * 256;
        const int xr = (prow & 15) << 4;
        const float m = mrow[mi][j];
        float psum = 0.f;
        #pragma unroll
        for (int ni = 0; ni < 8; ni++) {
          float p = __builtin_amdgcn_exp2f(sacc[mi][ni][j] - m);
          psum += p;
          *(unsigned short*)(pb + (((ni * 16 + l15) * 2) ^ xr)) = f2bf(p);
        }
        psum += __shfl_xor(psum, 1);
        psum += __shfl_xor(psum, 2);
        psum += __shfl_xor(psum, 4);
        psum += __shfl_xor(psum, 8);
        lrow[mi][j] += psum;
      }
    }

    // ---- O += P V ----
    #pragma unroll
    for (int ks = 0; ks < 4; ks++) {
      bf16x8 pa[2], vb[6];
      #pragma unroll
      for (int mi = 0; mi < 2; mi++)
        pa[mi] = *(const bf16x8*)(PsW + (mi * 16 + l15) * 256 + ((ks * 64 + l16 * 16) ^ (l15 << 4)));
      #pragma unroll
      for (int ni = 0; ni < 6; ni++)
        vb[ni] = *(const bf16x8*)((const char*)Vs + (ni * 16 + l15) * 256 +
                                  ((ks * 64 + l16 * 16) ^ ((l15 & 7) << 4)));
      __builtin_amdgcn_s_setprio(1);
      #pragma unroll
      for (int mi = 0; mi < 2; mi++)
        #pragma unroll
        for (int ni = 0; ni < 6; ni++)
          oacc[mi][ni] = __builtin_amdgcn_mfma_f32_16x16x32_bf16(pa[mi], vb[ni], oacc[mi][ni], 0, 0, 0);
      __builtin_amdgcn_s_setprio(0);
    }
  }

  // epilogue: normalize, write [b][n][h*96+d] bf16
  unsigned short* Og = Oa + ((size_t)bi * SEQ + q0 + wid * 32) * EMBED + h * HDIM;
  #pragma unroll
  for (int mi = 0; mi < 2; mi++)
    #pragma unroll
    for (int ni = 0; ni < 6; ni++)
      #pragma unroll
      for (int j = 0; j < 4; j++) {
        int r = mi * 16 + l16 * 4 + j;
        float v = oacc[mi][ni][j] / lrow[mi][j];
        Og[(size_t)r * EMBED + ni * 16 + l15] = f2bf(v);
      }
}

extern "C" void kernel_launch(void* const* d_in, const int* in_sizes, int n_in,
                              void* d_out, int out_size, void* d_ws, size_t ws_size,
                              hipStream_t stream) {
  const float* x      = (const float*)d_in[0];
  const float* W_qkv  = (const float*)d_in[1];
  const float* b_qkv  = (const float*)d_in[2];
  const float* W_proj = (const float*)d_in[3];
  const float* b_proj = (const float*)d_in[4];
  float* out = (float*)d_out;

  char* ws = (char*)d_ws;
  size_t off = 0;
  auto alloc = [&](size_t bytes) { void* p = ws + off; off += (bytes + 255) & ~(size_t)255; return p; };
  unsigned short* xb  = (unsigned short*)alloc((size_t)NTOK * EMBED * 2);
  unsigned short* WqT = (unsigned short*)alloc((size_t)QKVN * EMBED * 2);
  unsigned short* WpT = (unsigned short*)alloc((size_t)EMBED * EMBED * 2);
  unsigned short* Qb  = (unsigned short*)alloc((size_t)NTOK * EMBED * 2);
  unsigned short* Kb  = (unsigned short*)alloc((size_t)NTOK * EMBED * 2);
  unsigned short* Vtb = (unsigned short*)alloc((size_t)NTOK * EMBED * 2);
  unsigned short* Ob  = (unsigned short*)alloc((size_t)NTOK * EMBED * 2);

  cast_x_kernel<<<dim3(NTOK * EMBED / 4 / 256), dim3(256), 0, stream>>>(
      (const float4*)x, (ushort4*)xb, NTOK * EMBED / 4);
  transpose_cast_kernel<<<dim3(QKVN / 32, EMBED / 32), dim3(256), 0, stream>>>(W_qkv, WqT, EMBED, QKVN);
  transpose_cast_kernel<<<dim3(EMBED / 32, EMBED / 32), dim3(256), 0, stream>>>(W_proj, WpT, EMBED, EMBED);

  gemm_kernel<0><<<dim3(QKVN / 128, NTOK / 128), dim3(256), 0, stream>>>(
      xb, WqT, b_qkv, EMBED, Qb, Kb, Vtb, nullptr);

  attn_kernel<<<dim3(BATCH * NHEADS * (SEQ / 128)), dim3(256), 0, stream>>>(Qb, Kb, Vtb, Ob);

  gemm_kernel<1><<<dim3(EMBED / 128, NTOK / 128), dim3(256), 0, stream>>>(
      Ob, WpT, b_proj, EMBED, nullptr, nullptr, nullptr, out);
}

// Round 3
// 278.429 us; speedup vs baseline: 1.1145x; 1.1145x over previous
//
#include <hip/hip_runtime.h>
#include <hip/hip_bf16.h>

#define EMBED 768
#define NHEADS 8
#define HDIM 96
#define SEQ 2048
#define BATCH 4
#define NTOK (BATCH*SEQ)   // 8192
#define QKVN (3*EMBED)     // 2304

// 1/sqrt(96) * log2(e): softmax computed in exp2 domain
#define QSCALE 0.14724444f

typedef __attribute__((ext_vector_type(4))) float f32x4;
typedef __attribute__((ext_vector_type(8))) __bf16 bf16x8;

__device__ __forceinline__ unsigned short f2bf(float f) {
  union { float f; unsigned int u; } c; c.f = f;
  unsigned int u = c.u;
  return (unsigned short)((u + 0x7FFFu + ((u >> 16) & 1u)) >> 16);
}

__device__ __forceinline__ void gload_lds16(const void* g, void* l) {
  __builtin_amdgcn_global_load_lds(
      (const __attribute__((address_space(1))) unsigned int*)g,
      (__attribute__((address_space(3))) unsigned int*)l, 16, 0, 0);
}

// ---------------- cast x -> bf16 ----------------
__global__ __launch_bounds__(256) void cast_x_kernel(const float4* __restrict__ in,
                                                     ushort4* __restrict__ out, int n4) {
  int i = blockIdx.x * 256 + threadIdx.x;
  if (i >= n4) return;
  float4 v = in[i];
  out[i] = make_ushort4(f2bf(v.x), f2bf(v.y), f2bf(v.z), f2bf(v.w));
}

// ---------------- transpose+cast W [R][C] f32 -> [C][R] bf16 ----------------
__global__ __launch_bounds__(256) void transpose_cast_kernel(const float* __restrict__ in,
                                                             unsigned short* __restrict__ out,
                                                             int R, int C) {
  __shared__ float t[32][33];
  int c0 = blockIdx.x * 32, r0 = blockIdx.y * 32;
  int tx = threadIdx.x & 31, ty = threadIdx.x >> 5;  // 32 x 8
  #pragma unroll
  for (int i = 0; i < 32; i += 8)
    t[ty + i][tx] = in[(size_t)(r0 + ty + i) * C + c0 + tx];
  __syncthreads();
  #pragma unroll
  for (int i = 0; i < 32; i += 8)
    out[(size_t)(c0 + ty + i) * R + r0 + tx] = f2bf(t[tx][ty + i]);
}

// ---------------- GEMM: A[M][K] bf16 x B[N][K] bf16, double-buffered 2-phase ----------------
template <int MODE>
__global__ __launch_bounds__(256) void gemm_kernel(
    const unsigned short* __restrict__ A, const unsigned short* __restrict__ B,
    const float* __restrict__ bias, int K,
    unsigned short* __restrict__ Qo, unsigned short* __restrict__ Ko,
    unsigned short* __restrict__ Vt, float* __restrict__ out) {
  __shared__ unsigned short As[2][128][32];  // 16 KB
  __shared__ unsigned short Bs[2][128][32];  // 16 KB
  const int tid = threadIdx.x;
  const int lane = tid & 63, wid = tid >> 6;
  const int wr = wid >> 1, wc = wid & 1;
  const int l15 = lane & 15, l16 = lane >> 4;
  const int m0 = blockIdx.y * 128, n0 = blockIdx.x * 128;

  auto stage = [&](int buf, int k0) {
    #pragma unroll
    for (int i = 0; i < 2; i++) {
      int chunk = i * 256 + tid;
      gload_lds16(A + (size_t)(m0 + (chunk >> 2)) * K + k0 + (chunk & 3) * 8,
                  (char*)&As[buf][0][0] + (i * 256 + wid * 64) * 16);
      gload_lds16(B + (size_t)(n0 + (chunk >> 2)) * K + k0 + (chunk & 3) * 8,
                  (char*)&Bs[buf][0][0] + (i * 256 + wid * 64) * 16);
    }
  };

  f32x4 acc[4][4] = {};

  stage(0, 0);
  __syncthreads();
  int cur = 0;
  for (int k0 = 0; k0 < K; k0 += 32, cur ^= 1) {
    if (k0 + 32 < K) stage(cur ^ 1, k0 + 32);

    bf16x8 af[4], bfr[4];
    #pragma unroll
    for (int mi = 0; mi < 4; mi++)
      af[mi] = *(const bf16x8*)&As[cur][wr * 64 + mi * 16 + l15][l16 * 8];
    #pragma unroll
    for (int ni = 0; ni < 4; ni++)
      bfr[ni] = *(const bf16x8*)&Bs[cur][wc * 64 + ni * 16 + l15][l16 * 8];
    #pragma unroll
    for (int mi = 0; mi < 4; mi++)
      #pragma unroll
      for (int ni = 0; ni < 4; ni++)
        acc[mi][ni] = __builtin_amdgcn_mfma_f32_16x16x32_bf16(af[mi], bfr[ni], acc[mi][ni], 0, 0, 0);

    __syncthreads();  // drains prefetch vmcnt + gates buffer reuse
  }

  if (MODE == 0) {
    #pragma unroll
    for (int mi = 0; mi < 4; mi++) {
      #pragma unroll
      for (int ni = 0; ni < 4; ni++) {
        int col = n0 + wc * 64 + ni * 16 + l15;   // 0..2303
        int h = col / 288;
        int rem = col - h * 288;
        int d = rem / 3;
        int which = rem - d * 3;
        float bb = bias[col];
        #pragma unroll
        for (int j = 0; j < 4; j++) {
          int row = m0 + wr * 64 + mi * 16 + l16 * 4 + j;  // token 0..8191
          int bi = row >> 11, nn = row & 2047;
          float v = acc[mi][ni][j] + bb;
          size_t bh = (size_t)(bi * NHEADS + h);
          if (which == 0)      Qo[(bh * SEQ + nn) * HDIM + d] = f2bf(v * QSCALE);
          else if (which == 1) Ko[(bh * SEQ + nn) * HDIM + d] = f2bf(v);
          else                 Vt[(bh * HDIM + d) * SEQ + nn] = f2bf(v);
        }
      }
    }
  } else {
    #pragma unroll
    for (int mi = 0; mi < 4; mi++) {
      #pragma unroll
      for (int ni = 0; ni < 4; ni++) {
        int col = n0 + wc * 64 + ni * 16 + l15;
        float bb = bias[col];
        #pragma unroll
        for (int j = 0; j < 4; j++) {
          int row = m0 + wr * 64 + mi * 16 + l16 * 4 + j;
          out[(size_t)row * EMBED + col] = acc[mi][ni][j] + bb;
        }
      }
    }
  }
}

// ---------------- flash attention ----------------
// Q [B*H][N][96] bf16 (pre-scaled by 1/sqrt(96)*log2e), K same layout,
// Vt [B*H][96][N] bf16. Out: attn [B][N][H*96] bf16.
// KVBLK=64, QBLK=128 (4 waves x 32 rows), K/V double-buffered, 1 barrier/iter.
__global__ __launch_bounds__(256) void attn_kernel(
    const unsigned short* __restrict__ Q, const unsigned short* __restrict__ Kd,
    const unsigned short* __restrict__ Vt, unsigned short* __restrict__ Oa) {
  __shared__ unsigned short Ks[2][64 * 96];   // 24 KB
  __shared__ unsigned short Vs[2][96 * 64];   // 24 KB ([d][k], rows XOR-swizzled)
  __shared__ unsigned short Ps[4][32 * 64];   // 16 KB per-wave [32][64], XOR-swizzled

  const int tid = threadIdx.x, lane = tid & 63, wid = tid >> 6;
  const int l15 = lane & 15, l16 = lane >> 4;
  // XCD swizzle: 512 blocks, 8 XCDs -> each XCD owns 4 consecutive (b,h)
  const int bid = blockIdx.x;
  const int swz = (bid & 7) * 64 + (bid >> 3);
  const int qb = swz & 15, bh = swz >> 4;
  const int bi = bh >> 3, h = bh & 7;
  const int q0 = qb * 128;

  const unsigned short* Qg = Q + ((size_t)bh * SEQ + q0) * HDIM;
  const unsigned short* Kg = Kd + (size_t)bh * SEQ * HDIM;
  const unsigned short* Vg = Vt + (size_t)bh * HDIM * SEQ;

  // Q fragments hoisted to registers (loop-invariant, wave-private rows)
  bf16x8 qf[2][3];
  #pragma unroll
  for (int mi = 0; mi < 2; mi++)
    #pragma unroll
    for (int ks = 0; ks < 3; ks++)
      qf[mi][ks] = *(const bf16x8*)(Qg + (size_t)(wid * 32 + mi * 16 + l15) * HDIM + ks * 32 + l16 * 8);

  auto stageKV = [&](int buf, int k0) {
    #pragma unroll
    for (int i = 0; i < 3; i++) {  // K tile: 64x96 contiguous = 768 chunks
      int idx = i * 256 + tid;
      gload_lds16(Kg + (size_t)k0 * HDIM + idx * 8,
                  (char*)&Ks[buf][0] + (i * 256 + wid * 64) * 16);
    }
    #pragma unroll
    for (int i = 0; i < 3; i++) {  // V^T tile: 96 rows x 64, swizzled source
      int idx = i * 256 + tid;
      int d = idx >> 3, slot = idx & 7;
      gload_lds16(Vg + (size_t)d * SEQ + k0 + ((slot ^ (d & 7)) << 3),
                  (char*)&Vs[buf][0] + (i * 256 + wid * 64) * 16);
    }
  };

  f32x4 oacc[2][6] = {};
  float mrow[2][4], lrow[2][4];
  #pragma unroll
  for (int mi = 0; mi < 2; mi++)
    #pragma unroll
    for (int j = 0; j < 4; j++) { mrow[mi][j] = -__builtin_inff(); lrow[mi][j] = 0.f; }

  char* PsW = (char*)&Ps[wid][0];

  stageKV(0, 0);
  __syncthreads();

  for (int kb = 0; kb < SEQ / 64; kb++) {
    const int cur = kb & 1;
    if (kb + 1 < SEQ / 64) stageKV(cur ^ 1, (kb + 1) * 64);

    // ---- S = Q K^T (rows wid*32+mi*16+l16*4+j, cols ni*16+l15) ----
    const char* Kb_ = (const char*)&Ks[cur][0];
    f32x4 sacc[2][4] = {};
    #pragma unroll
    for (int ks = 0; ks < 3; ks++) {
      bf16x8 bk[4];
      #pragma unroll
      for (int ni = 0; ni < 4; ni++)
        bk[ni] = *(const bf16x8*)(Kb_ + (ni * 16 + l15) * 192 + ks * 64 + l16 * 16);
      #pragma unroll
      for (int mi = 0; mi < 2; mi++)
        #pragma unroll
        for (int ni = 0; ni < 4; ni++)
          sacc[mi][ni] = __builtin_amdgcn_mfma_f32_16x16x32_bf16(qf[mi][ks], bk[ni], sacc[mi][ni], 0, 0, 0);
    }

    // ---- tile row-maxima ----
    float tmax[2][4];
    float g = -3.4e38f;
    #pragma unroll
    for (int mi = 0; mi < 2; mi++) {
      #pragma unroll
      for (int j = 0; j < 4; j++) {
        float v = fmaxf(fmaxf(sacc[mi][0][j], sacc[mi][1][j]),
                        fmaxf(sacc[mi][2][j], sacc[mi][3][j]));
        v = fmaxf(v, __shfl_xor(v, 1));
        v = fmaxf(v, __shfl_xor(v, 2));
        v = fmaxf(v, __shfl_xor(v, 4));
        v = fmaxf(v, __shfl_xor(v, 8));
        tmax[mi][j] = v;
        g = fmaxf(g, v - mrow[mi][j]);
      }
    }
    // T13 defer-max: THR = 8*log2e (exp2 domain)
    if (!__all(g <= 11.54f)) {
      #pragma unroll
      for (int mi = 0; mi < 2; mi++) {
        #pragma unroll
        for (int j = 0; j < 4; j++) {
          float mnew = fmaxf(mrow[mi][j], tmax[mi][j]);
          float alpha = __builtin_amdgcn_exp2f(mrow[mi][j] - mnew);
          mrow[mi][j] = mnew;
          lrow[mi][j] *= alpha;
          #pragma unroll
          for (int ni = 0; ni < 6; ni++) {
            oacc[mi][ni][0] *= alpha; oacc[mi][ni][1] *= alpha;
            oacc[mi][ni][2] *= alpha; oacc[mi][ni][3] *= alpha;
          }
        }
      }
    }

    // ---- P = exp2(S - m); write swizzled per-wave LDS; accumulate l ----
    #pragma unroll
    for (int mi = 0; mi < 2; mi++) {
      #pragma unroll
      for (int j = 0; j < 4; j++) {
        const int prow = mi * 16 + l16 * 4 + j;
        char* pb = PsW + prow * 128;
        const int xr = (prow & 7) << 4;
        const float m = mrow[mi][j];
        float psum = 0.f;
        #pragma unroll
        for (int ni = 0; ni < 4; ni++) {
          float p = __builtin_amdgcn_exp2f(sacc[mi][ni][j] - m);
          psum += p;
          *(unsigned short*)(pb + (((ni * 16 + l15) * 2) ^ xr)) = f2bf(p);
        }
        psum += __shfl_xor(psum, 1);
        psum += __shfl_xor(psum, 2);
        psum += __shfl_xor(psum, 4);
        psum += __shfl_xor(psum, 8);
        lrow[mi][j] += psum;
      }
    }

    // ---- O += P V ----
    const char* Vb_ = (const char*)&Vs[cur][0];
    #pragma unroll
    for (int ks = 0; ks < 2; ks++) {
      bf16x8 pa[2], vb[6];
      #pragma unroll
      for (int mi = 0; mi < 2; mi++)
        pa[mi] = *(const bf16x8*)(PsW + (mi * 16 + l15) * 128 +
                                  ((ks * 64 + l16 * 16) ^ ((l15 & 7) << 4)));
      #pragma unroll
      for (int ni = 0; ni < 6; ni++)
        vb[ni] = *(const bf16x8*)(Vb_ + (ni * 16 + l15) * 128 +
                                  ((ks * 64 + l16 * 16) ^ ((l15 & 7) << 4)));
      #pragma unroll
      for (int mi = 0; mi < 2; mi++)
        #pragma unroll
        for (int ni = 0; ni < 6; ni++)
          oacc[mi][ni] = __builtin_amdgcn_mfma_f32_16x16x32_bf16(pa[mi], vb[ni], oacc[mi][ni], 0, 0, 0);
    }

    __syncthreads();  // drains prefetch vmcnt + gates buffer reuse
  }

  // epilogue: normalize, write [b][n][h*96+d] bf16
  unsigned short* Og = Oa + ((size_t)bi * SEQ + q0 + wid * 32) * EMBED + h * HDIM;
  #pragma unroll
  for (int mi = 0; mi < 2; mi++)
    #pragma unroll
    for (int ni = 0; ni < 6; ni++)
      #pragma unroll
      for (int j = 0; j < 4; j++) {
        int r = mi * 16 + l16 * 4 + j;
        float v = oacc[mi][ni][j] / lrow[mi][j];
        Og[(size_t)r * EMBED + ni * 16 + l15] = f2bf(v);
      }
}

extern "C" void kernel_launch(void* const* d_in, const int* in_sizes, int n_in,
                              void* d_out, int out_size, void* d_ws, size_t ws_size,
                              hipStream_t stream) {
  const float* x      = (const float*)d_in[0];
  const float* W_qkv  = (const float*)d_in[1];
  const float* b_qkv  = (const float*)d_in[2];
  const float* W_proj = (const float*)d_in[3];
  const float* b_proj = (const float*)d_in[4];
  float* out = (float*)d_out;

  char* ws = (char*)d_ws;
  size_t off = 0;
  auto alloc = [&](size_t bytes) { void* p = ws + off; off += (bytes + 255) & ~(size_t)255; return p; };
  unsigned short* xb  = (unsigned short*)alloc((size_t)NTOK * EMBED * 2);
  unsigned short* WqT = (unsigned short*)alloc((size_t)QKVN * EMBED * 2);
  unsigned short* WpT = (unsigned short*)alloc((size_t)EMBED * EMBED * 2);
  unsigned short* Qb  = (unsigned short*)alloc((size_t)NTOK * EMBED * 2);
  unsigned short* Kb  = (unsigned short*)alloc((size_t)NTOK * EMBED * 2);
  unsigned short* Vtb = (unsigned short*)alloc((size_t)NTOK * EMBED * 2);
  unsigned short* Ob  = (unsigned short*)alloc((size_t)NTOK * EMBED * 2);

  cast_x_kernel<<<dim3(NTOK * EMBED / 4 / 256), dim3(256), 0, stream>>>(
      (const float4*)x, (ushort4*)xb, NTOK * EMBED / 4);
  transpose_cast_kernel<<<dim3(QKVN / 32, EMBED / 32), dim3(256), 0, stream>>>(W_qkv, WqT, EMBED, QKVN);
  transpose_cast_kernel<<<dim3(EMBED / 32, EMBED / 32), dim3(256), 0, stream>>>(W_proj, WpT, EMBED, EMBED);

  gemm_kernel<0><<<dim3(QKVN / 128, NTOK / 128), dim3(256), 0, stream>>>(
      xb, WqT, b_qkv, EMBED, Qb, Kb, Vtb, nullptr);

  attn_kernel<<<dim3(BATCH * NHEADS * (SEQ / 128)), dim3(256), 0, stream>>>(Qb, Kb, Vtb, Ob);

  gemm_kernel<1><<<dim3(EMBED / 128, NTOK / 128), dim3(256), 0, stream>>>(
      Ob, WpT, b_proj, EMBED, nullptr, nullptr, nullptr, out);
}

// Round 4
// 187.236 us; speedup vs baseline: 1.6572x; 1.4870x over previous
//
#include <hip/hip_runtime.h>
#include <hip/hip_bf16.h>

#define EMBED 768
#define NHEADS 8
#define HDIM 96
#define SEQ 2048
#define BATCH 4
#define NTOK (BATCH*SEQ)   // 8192
#define QKVN (3*EMBED)     // 2304

// 1/sqrt(96) * log2(e): softmax computed in exp2 domain
#define QSCALE 0.14724444f

typedef __attribute__((ext_vector_type(4))) float f32x4;
typedef __attribute__((ext_vector_type(8))) __bf16 bf16x8;

__device__ __forceinline__ unsigned short f2bf(float f) {
  union { float f; unsigned int u; } c; c.f = f;
  unsigned int u = c.u;
  return (unsigned short)((u + 0x7FFFu + ((u >> 16) & 1u)) >> 16);
}

__device__ __forceinline__ void gload_lds16(const void* g, void* l) {
  __builtin_amdgcn_global_load_lds(
      (const __attribute__((address_space(1))) unsigned int*)g,
      (__attribute__((address_space(3))) unsigned int*)l, 16, 0, 0);
}

// ---------------- cast x -> bf16 ----------------
__global__ __launch_bounds__(256) void cast_x_kernel(const float4* __restrict__ in,
                                                     ushort4* __restrict__ out, int n4) {
  int i = blockIdx.x * 256 + threadIdx.x;
  if (i >= n4) return;
  float4 v = in[i];
  out[i] = make_ushort4(f2bf(v.x), f2bf(v.y), f2bf(v.z), f2bf(v.w));
}

// ---------------- transpose+cast W [R][C] f32 -> [C][R] bf16 ----------------
__global__ __launch_bounds__(256) void transpose_cast_kernel(const float* __restrict__ in,
                                                             unsigned short* __restrict__ out,
                                                             int R, int C) {
  __shared__ float t[32][33];
  int c0 = blockIdx.x * 32, r0 = blockIdx.y * 32;
  int tx = threadIdx.x & 31, ty = threadIdx.x >> 5;  // 32 x 8
  #pragma unroll
  for (int i = 0; i < 32; i += 8)
    t[ty + i][tx] = in[(size_t)(r0 + ty + i) * C + c0 + tx];
  __syncthreads();
  #pragma unroll
  for (int i = 0; i < 32; i += 8)
    out[(size_t)(c0 + ty + i) * R + r0 + tx] = f2bf(t[tx][ty + i]);
}

// ---------------- GEMM: A[M][K] bf16 x B[N][K] bf16, double-buffered 2-phase ----------------
template <int MODE>
__global__ __launch_bounds__(256) void gemm_kernel(
    const unsigned short* __restrict__ A, const unsigned short* __restrict__ B,
    const float* __restrict__ bias, int K,
    unsigned short* __restrict__ Qo, unsigned short* __restrict__ Ko,
    unsigned short* __restrict__ Vt, float* __restrict__ out) {
  __shared__ unsigned short As[2][128][32];  // 16 KB
  __shared__ unsigned short Bs[2][128][32];  // 16 KB
  const int tid = threadIdx.x;
  const int lane = tid & 63, wid = tid >> 6;
  const int wr = wid >> 1, wc = wid & 1;
  const int l15 = lane & 15, l16 = lane >> 4;
  const int m0 = blockIdx.y * 128, n0 = blockIdx.x * 128;

  auto stage = [&](int buf, int k0) {
    #pragma unroll
    for (int i = 0; i < 2; i++) {
      int chunk = i * 256 + tid;
      gload_lds16(A + (size_t)(m0 + (chunk >> 2)) * K + k0 + (chunk & 3) * 8,
                  (char*)&As[buf][0][0] + (i * 256 + wid * 64) * 16);
      gload_lds16(B + (size_t)(n0 + (chunk >> 2)) * K + k0 + (chunk & 3) * 8,
                  (char*)&Bs[buf][0][0] + (i * 256 + wid * 64) * 16);
    }
  };

  f32x4 acc[4][4] = {};

  stage(0, 0);
  __syncthreads();
  int cur = 0;
  for (int k0 = 0; k0 < K; k0 += 32, cur ^= 1) {
    if (k0 + 32 < K) stage(cur ^ 1, k0 + 32);

    bf16x8 af[4], bfr[4];
    #pragma unroll
    for (int mi = 0; mi < 4; mi++)
      af[mi] = *(const bf16x8*)&As[cur][wr * 64 + mi * 16 + l15][l16 * 8];
    #pragma unroll
    for (int ni = 0; ni < 4; ni++)
      bfr[ni] = *(const bf16x8*)&Bs[cur][wc * 64 + ni * 16 + l15][l16 * 8];
    #pragma unroll
    for (int mi = 0; mi < 4; mi++)
      #pragma unroll
      for (int ni = 0; ni < 4; ni++)
        acc[mi][ni] = __builtin_amdgcn_mfma_f32_16x16x32_bf16(af[mi], bfr[ni], acc[mi][ni], 0, 0, 0);

    __syncthreads();
  }

  if (MODE == 0) {
    #pragma unroll
    for (int mi = 0; mi < 4; mi++) {
      #pragma unroll
      for (int ni = 0; ni < 4; ni++) {
        int col = n0 + wc * 64 + ni * 16 + l15;   // 0..2303
        int h = col / 288;
        int rem = col - h * 288;
        int d = rem / 3;
        int which = rem - d * 3;
        float bb = bias[col];
        #pragma unroll
        for (int j = 0; j < 4; j++) {
          int row = m0 + wr * 64 + mi * 16 + l16 * 4 + j;  // token 0..8191
          int bi = row >> 11, nn = row & 2047;
          float v = acc[mi][ni][j] + bb;
          size_t bh = (size_t)(bi * NHEADS + h);
          if (which == 0)      Qo[(bh * SEQ + nn) * HDIM + d] = f2bf(v * QSCALE);
          else if (which == 1) Ko[(bh * SEQ + nn) * HDIM + d] = f2bf(v);
          else                 Vt[(bh * HDIM + d) * SEQ + nn] = f2bf(v);
        }
      }
    }
  } else {
    #pragma unroll
    for (int mi = 0; mi < 4; mi++) {
      #pragma unroll
      for (int ni = 0; ni < 4; ni++) {
        int col = n0 + wc * 64 + ni * 16 + l15;
        float bb = bias[col];
        #pragma unroll
        for (int j = 0; j < 4; j++) {
          int row = m0 + wr * 64 + mi * 16 + l16 * 4 + j;
          out[(size_t)row * EMBED + col] = acc[mi][ni][j] + bb;
        }
      }
    }
  }
}

// ---------------- flash attention (swapped QK^T: S^T / O^T in-register) ----------------
// Q [B*H][N][96] bf16 (pre-scaled by 1/sqrt(96)*log2e), K same layout,
// Vt [B*H][96][N] bf16. Out: attn [B][N][H*96] bf16.
// KVBLK=64 single-buffered (2 barriers/iter), QBLK=128 (4 waves x 32 rows).
// LDS = 12K (K) + 12K (V) + 16K (P) = 40960 B -> 3-4 blocks/CU.
__global__ __launch_bounds__(256) void attn_kernel(
    const unsigned short* __restrict__ Q, const unsigned short* __restrict__ Kd,
    const unsigned short* __restrict__ Vt, unsigned short* __restrict__ Oa) {
  __shared__ unsigned short Ks[64 * 96];    // 12 KB row-major [64][96]
  __shared__ unsigned short Vs[96 * 64];    // 12 KB [d][k], rows XOR-swizzled
  __shared__ unsigned short Ps[4][32 * 64]; // 16 KB per-wave [32 q][64 k], swizzled

  const int tid = threadIdx.x, lane = tid & 63, wid = tid >> 6;
  const int l15 = lane & 15, l16 = lane >> 4;
  // XCD swizzle: 512 blocks, 8 XCDs -> each XCD owns 4 consecutive (b,h)
  const int bid = blockIdx.x;
  const int swz = (bid & 7) * 64 + (bid >> 3);
  const int qb_ = swz & 15, bh = swz >> 4;
  const int bi = bh >> 3, h = bh & 7;
  const int q0 = qb_ * 128;

  const unsigned short* Qg = Q + ((size_t)bh * SEQ + q0) * HDIM;
  const unsigned short* Kg = Kd + (size_t)bh * SEQ * HDIM;
  const unsigned short* Vg = Vt + (size_t)bh * HDIM * SEQ;

  // Q as MFMA B-fragments (n = q = l15, k-octet = l16), hoisted to registers
  bf16x8 qf[2][3];
  #pragma unroll
  for (int qb = 0; qb < 2; qb++)
    #pragma unroll
    for (int ks = 0; ks < 3; ks++)
      qf[qb][ks] = *(const bf16x8*)(Qg + (size_t)(wid * 32 + qb * 16 + l15) * HDIM + ks * 32 + l16 * 8);

  auto stageKV = [&](int k0) {
    #pragma unroll
    for (int i = 0; i < 3; i++) {  // K tile: 64x96 contiguous
      int idx = i * 256 + tid;
      gload_lds16(Kg + (size_t)k0 * HDIM + idx * 8,
                  (char*)Ks + (i * 256 + wid * 64) * 16);
    }
    #pragma unroll
    for (int i = 0; i < 3; i++) {  // V^T tile: 96 rows x 64, swizzled source
      int idx = i * 256 + tid;
      int d = idx >> 3, slot = idx & 7;
      gload_lds16(Vg + (size_t)d * SEQ + k0 + ((slot ^ (d & 7)) << 3),
                  (char*)Vs + (i * 256 + wid * 64) * 16);
    }
  };

  f32x4 oacc[2][6] = {};          // O^T: [qb][dblk], lane: d=dblk*16+4*l16+j, q=qb*16+l15
  float mrow[2], lrow[2];
  mrow[0] = mrow[1] = -__builtin_inff();
  lrow[0] = lrow[1] = 0.f;

  char* pw = (char*)&Ps[wid][0];
  const int swzP = ((l15 & 7) << 4) ^ ((l15 & 8) << 2);  // row-derived XOR (row&15 == l15)

  for (int kb = 0; kb < SEQ / 64; kb++) {
    __syncthreads();               // all waves done reading previous K/V
    stageKV(kb * 64);
    __syncthreads();               // staging complete

    // ---- S^T = K Q^T : sacc[qb][ni], lane holds kv = 16*ni+4*l16+j, q = qb*16+l15 ----
    f32x4 sacc[2][4] = {};
    #pragma unroll
    for (int ks = 0; ks < 3; ks++) {
      bf16x8 ak[4];
      #pragma unroll
      for (int ni = 0; ni < 4; ni++)
        ak[ni] = *(const bf16x8*)((const char*)Ks + (ni * 16 + l15) * 192 + ks * 64 + l16 * 16);
      #pragma unroll
      for (int qb = 0; qb < 2; qb++)
        #pragma unroll
        for (int ni = 0; ni < 4; ni++)
          sacc[qb][ni] = __builtin_amdgcn_mfma_f32_16x16x32_bf16(ak[ni], qf[qb][ks], sacc[qb][ni], 0, 0, 0);
    }

    // ---- per-lane softmax (q fixed per lane) ----
    float tmax[2];
    float g = -3.4e38f;
    #pragma unroll
    for (int qb = 0; qb < 2; qb++) {
      float v = fmaxf(
          fmaxf(fmaxf(fmaxf(sacc[qb][0][0], sacc[qb][0][1]), fmaxf(sacc[qb][0][2], sacc[qb][0][3])),
                fmaxf(fmaxf(sacc[qb][1][0], sacc[qb][1][1]), fmaxf(sacc[qb][1][2], sacc[qb][1][3]))),
          fmaxf(fmaxf(fmaxf(sacc[qb][2][0], sacc[qb][2][1]), fmaxf(sacc[qb][2][2], sacc[qb][2][3])),
                fmaxf(fmaxf(sacc[qb][3][0], sacc[qb][3][1]), fmaxf(sacc[qb][3][2], sacc[qb][3][3]))));
      v = fmaxf(v, __shfl_xor(v, 16));
      v = fmaxf(v, __shfl_xor(v, 32));
      tmax[qb] = v;
      g = fmaxf(g, v - mrow[qb]);
    }
    // T13 defer-max: THR = 8*log2e (exp2 domain)
    if (!__all(g <= 11.54f)) {
      #pragma unroll
      for (int qb = 0; qb < 2; qb++) {
        float mnew = fmaxf(mrow[qb], tmax[qb]);
        float alpha = __builtin_amdgcn_exp2f(mrow[qb] - mnew);
        mrow[qb] = mnew;
        lrow[qb] *= alpha;
        #pragma unroll
        for (int d6 = 0; d6 < 6; d6++) {
          oacc[qb][d6][0] *= alpha; oacc[qb][d6][1] *= alpha;
          oacc[qb][d6][2] *= alpha; oacc[qb][d6][3] *= alpha;
        }
      }
    }

    // ---- P = exp2(S^T - m): pack k-quads, 1 ds_write_b64 per ni; accumulate l ----
    #pragma unroll
    for (int qb = 0; qb < 2; qb++) {
      const float m = mrow[qb];
      char* rowp = pw + (qb * 16 + l15) * 128;
      float psum = 0.f;
      #pragma unroll
      for (int ni = 0; ni < 4; ni++) {
        float p0 = __builtin_amdgcn_exp2f(sacc[qb][ni][0] - m);
        float p1 = __builtin_amdgcn_exp2f(sacc[qb][ni][1] - m);
        float p2 = __builtin_amdgcn_exp2f(sacc[qb][ni][2] - m);
        float p3 = __builtin_amdgcn_exp2f(sacc[qb][ni][3] - m);
        psum += (p0 + p1) + (p2 + p3);
        unsigned int w0 = (unsigned int)f2bf(p0) | ((unsigned int)f2bf(p1) << 16);
        unsigned int w1 = (unsigned int)f2bf(p2) | ((unsigned int)f2bf(p3) << 16);
        *(uint2*)(rowp + ((ni * 32 + l16 * 8) ^ swzP)) = make_uint2(w0, w1);
      }
      psum += __shfl_xor(psum, 16);
      psum += __shfl_xor(psum, 32);
      lrow[qb] += psum;
    }

    // ---- O^T += V P^T : oacc[qb][dblk] = mfma(A=V-frag, B=P-frag) ----
    #pragma unroll
    for (int ks = 0; ks < 2; ks++) {
      bf16x8 pf[2], vb[6];
      #pragma unroll
      for (int qb = 0; qb < 2; qb++)
        pf[qb] = *(const bf16x8*)(pw + (qb * 16 + l15) * 128 + ((ks * 64 + l16 * 16) ^ swzP));
      #pragma unroll
      for (int d6 = 0; d6 < 6; d6++)
        vb[d6] = *(const bf16x8*)((const char*)Vs + (d6 * 16 + l15) * 128 +
                                  ((ks * 64 + l16 * 16) ^ ((l15 & 7) << 4)));
      #pragma unroll
      for (int qb = 0; qb < 2; qb++)
        #pragma unroll
        for (int d6 = 0; d6 < 6; d6++)
          oacc[qb][d6] = __builtin_amdgcn_mfma_f32_16x16x32_bf16(vb[d6], pf[qb], oacc[qb][d6], 0, 0, 0);
    }
  }

  // epilogue: normalize, write out[token][h*96+d], 4 consecutive d per store
  #pragma unroll
  for (int qb = 0; qb < 2; qb++) {
    const float rl = 1.f / lrow[qb];
    const int tok = q0 + wid * 32 + qb * 16 + l15;
    unsigned short* Og = Oa + ((size_t)bi * SEQ + tok) * EMBED + h * HDIM;
    #pragma unroll
    for (int d6 = 0; d6 < 6; d6++) {
      ushort4 sv;
      sv.x = f2bf(oacc[qb][d6][0] * rl);
      sv.y = f2bf(oacc[qb][d6][1] * rl);
      sv.z = f2bf(oacc[qb][d6][2] * rl);
      sv.w = f2bf(oacc[qb][d6][3] * rl);
      *(ushort4*)(Og + d6 * 16 + l16 * 4) = sv;
    }
  }
}

extern "C" void kernel_launch(void* const* d_in, const int* in_sizes, int n_in,
                              void* d_out, int out_size, void* d_ws, size_t ws_size,
                              hipStream_t stream) {
  const float* x      = (const float*)d_in[0];
  const float* W_qkv  = (const float*)d_in[1];
  const float* b_qkv  = (const float*)d_in[2];
  const float* W_proj = (const float*)d_in[3];
  const float* b_proj = (const float*)d_in[4];
  float* out = (float*)d_out;

  char* ws = (char*)d_ws;
  size_t off = 0;
  auto alloc = [&](size_t bytes) { void* p = ws + off; off += (bytes + 255) & ~(size_t)255; return p; };
  unsigned short* xb  = (unsigned short*)alloc((size_t)NTOK * EMBED * 2);
  unsigned short* WqT = (unsigned short*)alloc((size_t)QKVN * EMBED * 2);
  unsigned short* WpT = (unsigned short*)alloc((size_t)EMBED * EMBED * 2);
  unsigned short* Qb  = (unsigned short*)alloc((size_t)NTOK * EMBED * 2);
  unsigned short* Kb  = (unsigned short*)alloc((size_t)NTOK * EMBED * 2);
  unsigned short* Vtb = (unsigned short*)alloc((size_t)NTOK * EMBED * 2);
  unsigned short* Ob  = (unsigned short*)alloc((size_t)NTOK * EMBED * 2);

  cast_x_kernel<<<dim3(NTOK * EMBED / 4 / 256), dim3(256), 0, stream>>>(
      (const float4*)x, (ushort4*)xb, NTOK * EMBED / 4);
  transpose_cast_kernel<<<dim3(QKVN / 32, EMBED / 32), dim3(256), 0, stream>>>(W_qkv, WqT, EMBED, QKVN);
  transpose_cast_kernel<<<dim3(EMBED / 32, EMBED / 32), dim3(256), 0, stream>>>(W_proj, WpT, EMBED, EMBED);

  gemm_kernel<0><<<dim3(QKVN / 128, NTOK / 128), dim3(256), 0, stream>>>(
      xb, WqT, b_qkv, EMBED, Qb, Kb, Vtb, nullptr);

  attn_kernel<<<dim3(BATCH * NHEADS * (SEQ / 128)), dim3(256), 0, stream>>>(Qb, Kb, Vtb, Ob);

  gemm_kernel<1><<<dim3(EMBED / 128, NTOK / 128), dim3(256), 0, stream>>>(
      Ob, WpT, b_proj, EMBED, nullptr, nullptr, nullptr, out);
}

// Round 5
// 184.508 us; speedup vs baseline: 1.6818x; 1.0148x over previous
//
#include <hip/hip_runtime.h>
#include <hip/hip_bf16.h>

#define EMBED 768
#define NHEADS 8
#define HDIM 96
#define SEQ 2048
#define BATCH 4
#define NTOK (BATCH*SEQ)   // 8192
#define QKVN (3*EMBED)     // 2304

// 1/sqrt(96) * log2(e): softmax computed in exp2 domain
#define QSCALE 0.14724444f

typedef __attribute__((ext_vector_type(4))) float f32x4;
typedef __attribute__((ext_vector_type(8))) __bf16 bf16x8;

__device__ __forceinline__ unsigned short f2bf(float f) {
  union { float f; unsigned int u; } c; c.f = f;
  unsigned int u = c.u;
  return (unsigned short)((u + 0x7FFFu + ((u >> 16) & 1u)) >> 16);
}

// v_cvt_pk_bf16_f32: packs (lo,hi) -> dword of 2 bf16, RNE (gfx950)
__device__ __forceinline__ unsigned int cvt_pk_bf16(float lo, float hi) {
  unsigned int r;
  asm("v_cvt_pk_bf16_f32 %0, %1, %2" : "=v"(r) : "v"(lo), "v"(hi));
  return r;
}

__device__ __forceinline__ void gload_lds16(const void* g, void* l) {
  __builtin_amdgcn_global_load_lds(
      (const __attribute__((address_space(1))) unsigned int*)g,
      (__attribute__((address_space(3))) unsigned int*)l, 16, 0, 0);
}

// ---------------- cast x -> bf16 ----------------
__global__ __launch_bounds__(256) void cast_x_kernel(const float4* __restrict__ in,
                                                     ushort4* __restrict__ out, int n4) {
  int i = blockIdx.x * 256 + threadIdx.x;
  if (i >= n4) return;
  float4 v = in[i];
  out[i] = make_ushort4(f2bf(v.x), f2bf(v.y), f2bf(v.z), f2bf(v.w));
}

// ---------------- transpose+cast W [R][C] f32 -> [C'][R] bf16 ----------------
// remap=1 (W_qkv): out row = (c%3)*768 + c/3  (de-interleave qkv -> [which][h][d])
__global__ __launch_bounds__(256) void transpose_cast_kernel(const float* __restrict__ in,
                                                             unsigned short* __restrict__ out,
                                                             int R, int C, int remap) {
  __shared__ float t[32][33];
  int c0 = blockIdx.x * 32, r0 = blockIdx.y * 32;
  int tx = threadIdx.x & 31, ty = threadIdx.x >> 5;  // 32 x 8
  #pragma unroll
  for (int i = 0; i < 32; i += 8)
    t[ty + i][tx] = in[(size_t)(r0 + ty + i) * C + c0 + tx];
  __syncthreads();
  #pragma unroll
  for (int i = 0; i < 32; i += 8) {
    int c = c0 + ty + i;
    int rp = remap ? (c % 3) * 768 + c / 3 : c;
    out[(size_t)rp * R + r0 + tx] = f2bf(t[tx][ty + i]);
  }
}

// ---------------- GEMM: A[M][K] bf16 x B[N][K] bf16, double-buffered, 1 barrier/iter ----
// MODE 0: B rows are de-interleaved qkv cols [which][h][d]; scatter Q/K/V.
//         V columns are pi-permuted within 64-groups (sigma order for attn PV).
// MODE 1: bias add, f32 out.
template <int MODE>
__global__ __launch_bounds__(256) void gemm_kernel(
    const unsigned short* __restrict__ A, const unsigned short* __restrict__ B,
    const float* __restrict__ bias, int K,
    unsigned short* __restrict__ Qo, unsigned short* __restrict__ Ko,
    unsigned short* __restrict__ Vt, float* __restrict__ out) {
  __shared__ unsigned short As[2][128][32];  // 16 KB
  __shared__ unsigned short Bs[2][128][32];  // 16 KB
  const int tid = threadIdx.x;
  const int lane = tid & 63, wid = tid >> 6;
  const int wr = wid >> 1, wc = wid & 1;
  const int l15 = lane & 15, l16 = lane >> 4;
  const int m0 = blockIdx.y * 128, n0 = blockIdx.x * 128;

  auto stage = [&](int buf, int k0) {
    #pragma unroll
    for (int i = 0; i < 2; i++) {
      int chunk = i * 256 + tid;
      gload_lds16(A + (size_t)(m0 + (chunk >> 2)) * K + k0 + (chunk & 3) * 8,
                  (char*)&As[buf][0][0] + (i * 256 + wid * 64) * 16);
      gload_lds16(B + (size_t)(n0 + (chunk >> 2)) * K + k0 + (chunk & 3) * 8,
                  (char*)&Bs[buf][0][0] + (i * 256 + wid * 64) * 16);
    }
  };

  f32x4 acc[4][4] = {};

  stage(0, 0);
  __syncthreads();
  int cur = 0;
  for (int k0 = 0; k0 < K; k0 += 32, cur ^= 1) {
    if (k0 + 32 < K) stage(cur ^ 1, k0 + 32);

    bf16x8 af[4], bfr[4];
    #pragma unroll
    for (int mi = 0; mi < 4; mi++)
      af[mi] = *(const bf16x8*)&As[cur][wr * 64 + mi * 16 + l15][l16 * 8];
    #pragma unroll
    for (int ni = 0; ni < 4; ni++)
      bfr[ni] = *(const bf16x8*)&Bs[cur][wc * 64 + ni * 16 + l15][l16 * 8];
    #pragma unroll
    for (int mi = 0; mi < 4; mi++)
      #pragma unroll
      for (int ni = 0; ni < 4; ni++)
        acc[mi][ni] = __builtin_amdgcn_mfma_f32_16x16x32_bf16(af[mi], bfr[ni], acc[mi][ni], 0, 0, 0);

    __syncthreads();
  }

  if (MODE == 0) {
    #pragma unroll
    for (int mi = 0; mi < 4; mi++) {
      #pragma unroll
      for (int ni = 0; ni < 4; ni++) {
        int base = n0 + wc * 64 + ni * 16;       // 16-aligned; one (which,h) per frag
        int which = base / 768;
        int hd = base - which * 768;             // h*96 + d0
        int h = hd / 96;
        int d0 = hd - h * 96;
        float bb = bias[hd * 3 + which + 3 * l15];  // original b_qkv index
        #pragma unroll
        for (int j = 0; j < 4; j++) {
          int row = m0 + wr * 64 + mi * 16 + l16 * 4 + j;  // token 0..8191
          int bi = row >> 11, nn = row & 2047;
          float v = acc[mi][ni][j] + bb;
          size_t bh = (size_t)(bi * NHEADS + h);
          if (which == 0)      Qo[(bh * SEQ + nn) * HDIM + d0 + l15] = f2bf(v * QSCALE);
          else if (which == 1) Ko[(bh * SEQ + nn) * HDIM + d0 + l15] = f2bf(v);
          else {
            // pi bit-permute within 64-group: sigma order for attn PV fragments
            int nn2 = (nn & ~63) | (nn & 32) | ((nn & 12) << 1) | ((nn & 16) >> 2) | (nn & 3);
            Vt[(bh * HDIM + d0 + l15) * SEQ + nn2] = f2bf(v);
          }
        }
      }
    }
  } else {
    #pragma unroll
    for (int mi = 0; mi < 4; mi++) {
      #pragma unroll
      for (int ni = 0; ni < 4; ni++) {
        int col = n0 + wc * 64 + ni * 16 + l15;
        float bb = bias[col];
        #pragma unroll
        for (int j = 0; j < 4; j++) {
          int row = m0 + wr * 64 + mi * 16 + l16 * 4 + j;
          out[(size_t)row * EMBED + col] = acc[mi][ni][j] + bb;
        }
      }
    }
  }
}

// ---------------- flash attention (swapped QK^T, P entirely in registers) ----------------
// Q [B*H][N][96] bf16 (pre-scaled), K same, Vt [B*H][96][N] bf16 with pi-permuted cols.
// Out: attn [B][N][H*96] bf16. KVBLK=64 double-buffered, 1 barrier/iter.
// LDS = 2*(12K + 12K) = 48 KB.
__global__ __launch_bounds__(256) void attn_kernel(
    const unsigned short* __restrict__ Q, const unsigned short* __restrict__ Kd,
    const unsigned short* __restrict__ Vt, unsigned short* __restrict__ Oa) {
  __shared__ unsigned short Ks[2][64 * 96];   // row-major [64][96]
  __shared__ unsigned short Vs[2][96 * 64];   // [d][sigma-k], 16B slots XOR (d&7)

  const int tid = threadIdx.x, lane = tid & 63, wid = tid >> 6;
  const int l15 = lane & 15, l16 = lane >> 4;
  // XCD swizzle: 512 blocks, 8 XCDs -> each XCD owns 4 consecutive (b,h)
  const int bid = blockIdx.x;
  const int swz = (bid & 7) * 64 + (bid >> 3);
  const int qb_ = swz & 15, bh = swz >> 4;
  const int bi = bh >> 3, h = bh & 7;
  const int q0 = qb_ * 128;

  const unsigned short* Qg = Q + ((size_t)bh * SEQ + q0) * HDIM;
  const unsigned short* Kg = Kd + (size_t)bh * SEQ * HDIM;
  const unsigned short* Vg = Vt + (size_t)bh * HDIM * SEQ;

  // Q as MFMA B-fragments (n = q = l15, k-octet = l16), hoisted to registers
  bf16x8 qf[2][3];
  #pragma unroll
  for (int qb = 0; qb < 2; qb++)
    #pragma unroll
    for (int ks = 0; ks < 3; ks++)
      qf[qb][ks] = *(const bf16x8*)(Qg + (size_t)(wid * 32 + qb * 16 + l15) * HDIM + ks * 32 + l16 * 8);

  auto stageKV = [&](int buf, int k0) {
    #pragma unroll
    for (int i = 0; i < 3; i++) {  // K tile: 64x96 contiguous
      int idx = i * 256 + tid;
      gload_lds16(Kg + (size_t)k0 * HDIM + idx * 8,
                  (char*)&Ks[buf][0] + (i * 256 + wid * 64) * 16);
    }
    #pragma unroll
    for (int i = 0; i < 3; i++) {  // V tile: 96 rows x 64 sigma-cols, bank-XOR on source
      int idx = i * 256 + tid;
      int d = idx >> 3, s = idx & 7;
      gload_lds16(Vg + (size_t)d * SEQ + k0 + ((s ^ (d & 7)) << 3),
                  (char*)&Vs[buf][0] + (i * 256 + wid * 64) * 16);
    }
  };

  f32x4 oacc[2][6] = {};          // O^T: [qb][d6], lane: d=d6*16+l16*4+j, q=qb*16+l15
  float mrow[2], lrow[2];
  mrow[0] = mrow[1] = -__builtin_inff();
  lrow[0] = lrow[1] = 0.f;

  stageKV(0, 0);
  __syncthreads();

  for (int kb = 0; kb < SEQ / 64; kb++) {
    const int cur = kb & 1;
    if (kb + 1 < SEQ / 64) stageKV(cur ^ 1, (kb + 1) * 64);

    const char* Kc = (const char*)&Ks[cur][0];
    const char* Vc = (const char*)&Vs[cur][0];

    // ---- S^T = K Q^T : lane holds kv = 16*ni+4*l16+j, q = qb*16+l15 ----
    f32x4 sacc[2][4] = {};
    #pragma unroll
    for (int ks = 0; ks < 3; ks++) {
      bf16x8 ak[4];
      #pragma unroll
      for (int ni = 0; ni < 4; ni++)
        ak[ni] = *(const bf16x8*)(Kc + (ni * 16 + l15) * 192 + ks * 64 + l16 * 16);
      #pragma unroll
      for (int qb = 0; qb < 2; qb++)
        #pragma unroll
        for (int ni = 0; ni < 4; ni++)
          sacc[qb][ni] = __builtin_amdgcn_mfma_f32_16x16x32_bf16(ak[ni], qf[qb][ks], sacc[qb][ni], 0, 0, 0);
    }

    // ---- per-lane softmax (q fixed per lane; reduce across l16 groups) ----
    float tmax[2];
    float g = -3.4e38f;
    #pragma unroll
    for (int qb = 0; qb < 2; qb++) {
      float a0 = fmaxf(fmaxf(sacc[qb][0][0], sacc[qb][0][1]), fmaxf(sacc[qb][0][2], sacc[qb][0][3]));
      float a1 = fmaxf(fmaxf(sacc[qb][1][0], sacc[qb][1][1]), fmaxf(sacc[qb][1][2], sacc[qb][1][3]));
      float a2 = fmaxf(fmaxf(sacc[qb][2][0], sacc[qb][2][1]), fmaxf(sacc[qb][2][2], sacc[qb][2][3]));
      float a3 = fmaxf(fmaxf(sacc[qb][3][0], sacc[qb][3][1]), fmaxf(sacc[qb][3][2], sacc[qb][3][3]));
      float v = fmaxf(fmaxf(a0, a1), fmaxf(a2, a3));
      v = fmaxf(v, __shfl_xor(v, 16));
      v = fmaxf(v, __shfl_xor(v, 32));
      tmax[qb] = v;
      g = fmaxf(g, v - mrow[qb]);
    }
    // T13 defer-max: THR = 8*log2e (exp2 domain)
    if (!__all(g <= 11.54f)) {
      #pragma unroll
      for (int qb = 0; qb < 2; qb++) {
        float mnew = fmaxf(mrow[qb], tmax[qb]);
        float alpha = __builtin_amdgcn_exp2f(mrow[qb] - mnew);
        mrow[qb] = mnew;
        lrow[qb] *= alpha;
        #pragma unroll
        for (int d6 = 0; d6 < 6; d6++) {
          oacc[qb][d6][0] *= alpha; oacc[qb][d6][1] *= alpha;
          oacc[qb][d6][2] *= alpha; oacc[qb][d6][3] *= alpha;
        }
      }
    }

    // ---- P = exp2(S^T - m), packed to bf16 IN REGISTERS; accumulate l ----
    unsigned int pk[2][8];  // [qb][ni*2 + half]
    #pragma unroll
    for (int qb = 0; qb < 2; qb++) {
      const float m = mrow[qb];
      float psum = 0.f;
      #pragma unroll
      for (int ni = 0; ni < 4; ni++) {
        float p0 = __builtin_amdgcn_exp2f(sacc[qb][ni][0] - m);
        float p1 = __builtin_amdgcn_exp2f(sacc[qb][ni][1] - m);
        float p2 = __builtin_amdgcn_exp2f(sacc[qb][ni][2] - m);
        float p3 = __builtin_amdgcn_exp2f(sacc[qb][ni][3] - m);
        psum += (p0 + p1) + (p2 + p3);
        pk[qb][ni * 2]     = cvt_pk_bf16(p0, p1);
        pk[qb][ni * 2 + 1] = cvt_pk_bf16(p2, p3);
      }
      psum += __shfl_xor(psum, 16);
      psum += __shfl_xor(psum, 32);
      lrow[qb] += psum;
    }

    // ---- O^T += V P^T : A = V sigma-fragment (b128), B = pk directly ----
    #pragma unroll
    for (int ks = 0; ks < 2; ks++) {
      bf16x8 vb[6];
      #pragma unroll
      for (int d6 = 0; d6 < 6; d6++)
        vb[d6] = *(const bf16x8*)(Vc + (d6 * 16 + l15) * 128 +
                                  (((ks * 4 + l16) ^ (l15 & 7)) << 4));
      #pragma unroll
      for (int qb = 0; qb < 2; qb++) {
        union { unsigned int u[4]; bf16x8 v; } pf;
        pf.u[0] = pk[qb][4 * ks];     pf.u[1] = pk[qb][4 * ks + 1];
        pf.u[2] = pk[qb][4 * ks + 2]; pf.u[3] = pk[qb][4 * ks + 3];
        #pragma unroll
        for (int d6 = 0; d6 < 6; d6++)
          oacc[qb][d6] = __builtin_amdgcn_mfma_f32_16x16x32_bf16(vb[d6], pf.v, oacc[qb][d6], 0, 0, 0);
      }
    }

    __syncthreads();  // drains prefetch vmcnt; gates buffer swap
  }

  // epilogue: normalize, write out[token][h*96+d], 8B per store
  #pragma unroll
  for (int qb = 0; qb < 2; qb++) {
    const float rl = 1.f / lrow[qb];
    const int tok = q0 + wid * 32 + qb * 16 + l15;
    unsigned short* Og = Oa + ((size_t)bi * SEQ + tok) * EMBED + h * HDIM;
    #pragma unroll
    for (int d6 = 0; d6 < 6; d6++) {
      uint2 o;
      o.x = cvt_pk_bf16(oacc[qb][d6][0] * rl, oacc[qb][d6][1] * rl);
      o.y = cvt_pk_bf16(oacc[qb][d6][2] * rl, oacc[qb][d6][3] * rl);
      *(uint2*)(Og + d6 * 16 + l16 * 4) = o;
    }
  }
}

extern "C" void kernel_launch(void* const* d_in, const int* in_sizes, int n_in,
                              void* d_out, int out_size, void* d_ws, size_t ws_size,
                              hipStream_t stream) {
  const float* x      = (const float*)d_in[0];
  const float* W_qkv  = (const float*)d_in[1];
  const float* b_qkv  = (const float*)d_in[2];
  const float* W_proj = (const float*)d_in[3];
  const float* b_proj = (const float*)d_in[4];
  float* out = (float*)d_out;

  char* ws = (char*)d_ws;
  size_t off = 0;
  auto alloc = [&](size_t bytes) { void* p = ws + off; off += (bytes + 255) & ~(size_t)255; return p; };
  unsigned short* xb  = (unsigned short*)alloc((size_t)NTOK * EMBED * 2);
  unsigned short* WqT = (unsigned short*)alloc((size_t)QKVN * EMBED * 2);
  unsigned short* WpT = (unsigned short*)alloc((size_t)EMBED * EMBED * 2);
  unsigned short* Qb  = (unsigned short*)alloc((size_t)NTOK * EMBED * 2);
  unsigned short* Kb  = (unsigned short*)alloc((size_t)NTOK * EMBED * 2);
  unsigned short* Vtb = (unsigned short*)alloc((size_t)NTOK * EMBED * 2);
  unsigned short* Ob  = (unsigned short*)alloc((size_t)NTOK * EMBED * 2);

  cast_x_kernel<<<dim3(NTOK * EMBED / 4 / 256), dim3(256), 0, stream>>>(
      (const float4*)x, (ushort4*)xb, NTOK * EMBED / 4);
  transpose_cast_kernel<<<dim3(QKVN / 32, EMBED / 32), dim3(256), 0, stream>>>(W_qkv, WqT, EMBED, QKVN, 1);
  transpose_cast_kernel<<<dim3(EMBED / 32, EMBED / 32), dim3(256), 0, stream>>>(W_proj, WpT, EMBED, EMBED, 0);

  gemm_kernel<0><<<dim3(QKVN / 128, NTOK / 128), dim3(256), 0, stream>>>(
      xb, WqT, b_qkv, EMBED, Qb, Kb, Vtb, nullptr);

  attn_kernel<<<dim3(BATCH * NHEADS * (SEQ / 128)), dim3(256), 0, stream>>>(Qb, Kb, Vtb, Ob);

  gemm_kernel<1><<<dim3(EMBED / 128, NTOK / 128), dim3(256), 0, stream>>>(
      Ob, WpT, b_proj, EMBED, nullptr, nullptr, nullptr, out);
}

// Round 6
// 157.631 us; speedup vs baseline: 1.9685x; 1.1705x over previous
//
#include <hip/hip_runtime.h>
#include <hip/hip_bf16.h>

#define EMBED 768
#define NHEADS 8
#define HDIM 96
#define SEQ 2048
#define BATCH 4
#define NTOK (BATCH*SEQ)   // 8192
#define QKVN (3*EMBED)     // 2304

// 1/sqrt(96) * log2(e): softmax computed in exp2 domain
#define QSCALE 0.14724444f

typedef __attribute__((ext_vector_type(4))) float f32x4;
typedef __attribute__((ext_vector_type(8))) __bf16 bf16x8;

__device__ __forceinline__ unsigned short f2bf(float f) {
  union { float f; unsigned int u; } c; c.f = f;
  unsigned int u = c.u;
  return (unsigned short)((u + 0x7FFFu + ((u >> 16) & 1u)) >> 16);
}

// v_cvt_pk_bf16_f32: packs (lo,hi) -> dword of 2 bf16 (gfx950)
__device__ __forceinline__ unsigned int cvt_pk_bf16(float lo, float hi) {
  unsigned int r;
  asm("v_cvt_pk_bf16_f32 %0, %1, %2" : "=v"(r) : "v"(lo), "v"(hi));
  return r;
}

__device__ __forceinline__ void gload_lds16(const void* g, void* l) {
  __builtin_amdgcn_global_load_lds(
      (const __attribute__((address_space(1))) unsigned int*)g,
      (__attribute__((address_space(3))) unsigned int*)l, 16, 0, 0);
}

// ---------------- cast x -> bf16 ----------------
__global__ __launch_bounds__(256) void cast_x_kernel(const float4* __restrict__ in,
                                                     ushort4* __restrict__ out, int n4) {
  int i = blockIdx.x * 256 + threadIdx.x;
  if (i >= n4) return;
  float4 v = in[i];
  out[i] = make_ushort4(f2bf(v.x), f2bf(v.y), f2bf(v.z), f2bf(v.w));
}

// ---------------- transpose+cast W [R][C] f32 -> [C'][R] bf16 ----------------
// remap=1 (W_qkv): out row = (c%3)*768 + c/3  (de-interleave qkv -> [which][h][d])
__global__ __launch_bounds__(256) void transpose_cast_kernel(const float* __restrict__ in,
                                                             unsigned short* __restrict__ out,
                                                             int R, int C, int remap) {
  __shared__ float t[32][33];
  int c0 = blockIdx.x * 32, r0 = blockIdx.y * 32;
  int tx = threadIdx.x & 31, ty = threadIdx.x >> 5;  // 32 x 8
  #pragma unroll
  for (int i = 0; i < 32; i += 8)
    t[ty + i][tx] = in[(size_t)(r0 + ty + i) * C + c0 + tx];
  __syncthreads();
  #pragma unroll
  for (int i = 0; i < 32; i += 8) {
    int c = c0 + ty + i;
    int rp = remap ? (c % 3) * 768 + c / 3 : c;
    out[(size_t)rp * R + r0 + tx] = f2bf(t[tx][ty + i]);
  }
}

// ---------------- GEMM, T2+T3/T4+T5 stack ----------------
// A[M][K] bf16 x B[N][K] bf16. BM=BN=128, BK=64, 4 waves, dbuf LDS (64 KB),
// raw barriers + counted waits (vmcnt(0) only at tile boundary, issued a full
// phase after the loads), XOR-swizzled LDS rows, setprio around MFMA.
// MODE 0: B rows are de-interleaved qkv cols [which][h][d]; scatter Q/K/V
//         (V pi-permuted + packed 8B stores). MODE 1: bias add, f32 out.
template <int MODE>
__global__ __launch_bounds__(256, 2) void gemm8_kernel(
    const unsigned short* __restrict__ A, const unsigned short* __restrict__ B,
    const float* __restrict__ bias, int K, int NB,
    unsigned short* __restrict__ Qo, unsigned short* __restrict__ Ko,
    unsigned short* __restrict__ Vt, float* __restrict__ out) {
  __shared__ unsigned short As[2][128 * 64];  // 32 KB (row stride 128 B, swizzled)
  __shared__ unsigned short Bs[2][128 * 64];  // 32 KB
  const int tid = threadIdx.x;
  const int lane = tid & 63, wid = tid >> 6;
  const int wr = wid >> 1, wc = wid & 1;
  const int l15 = lane & 15, l16 = lane >> 4;
  // bijective XCD swizzle (grid is a multiple of 8)
  const int cpx = gridDim.x >> 3;
  const int bid = blockIdx.x;
  const int swz = (bid & 7) * cpx + (bid >> 3);
  const int my = swz / NB, nx = swz - my * NB;
  const int m0 = my * 128, n0 = nx * 128;

  // stage half: 0 = A-tile (128x64), 1 = B-tile. Pre-swizzled global source
  // (slot s' = s ^ (r&7)); LDS dest linear (global_load_lds requirement).
  auto stage_half = [&](int buf, int kt, int half) {
    const unsigned short* src = half ? B : A;
    const int base0 = half ? n0 : m0;
    char* dst = (char*)(half ? &Bs[buf][0] : &As[buf][0]);
    #pragma unroll
    for (int i = 0; i < 4; i++) {
      int c = i * 256 + tid;            // per-lane chunk id
      int r = c >> 3, s = c & 7;
      gload_lds16(src + (size_t)(base0 + r) * K + kt * 64 + ((s ^ (r & 7)) << 3),
                  dst + (i * 256 + wid * 64) * 16);
    }
  };

  f32x4 acc[4][4] = {};
  const int xr = (l15 & 7) << 4;  // row-derived XOR key (row & 7 == l15 & 7)

  stage_half(0, 0, 0);
  stage_half(0, 0, 1);
  asm volatile("s_waitcnt vmcnt(0)" ::: "memory");
  __builtin_amdgcn_s_barrier();

  const int NT = K >> 6;
  for (int t = 0; t < NT; ++t) {
    const int cur = t & 1;
    const char* Ac = (const char*)&As[cur][0];
    const char* Bc = (const char*)&Bs[cur][0];
    #pragma unroll
    for (int kh = 0; kh < 2; ++kh) {
      bf16x8 af[4], bfr[4];
      #pragma unroll
      for (int mi = 0; mi < 4; mi++)
        af[mi] = *(const bf16x8*)(Ac + (wr * 64 + mi * 16 + l15) * 128 +
                                  ((kh * 64 + l16 * 16) ^ xr));
      #pragma unroll
      for (int ni = 0; ni < 4; ni++)
        bfr[ni] = *(const bf16x8*)(Bc + (wc * 64 + ni * 16 + l15) * 128 +
                                   ((kh * 64 + l16 * 16) ^ xr));
      if (t + 1 < NT) stage_half(cur ^ 1, t + 1, kh);  // loads stay in flight
      __builtin_amdgcn_s_barrier();
      __builtin_amdgcn_s_setprio(1);
      #pragma unroll
      for (int mi = 0; mi < 4; mi++)
        #pragma unroll
        for (int ni = 0; ni < 4; ni++)
          acc[mi][ni] = __builtin_amdgcn_mfma_f32_16x16x32_bf16(af[mi], bfr[ni], acc[mi][ni], 0, 0, 0);
      __builtin_amdgcn_s_setprio(0);
      __builtin_amdgcn_s_barrier();
    }
    // tile boundary: next tile's staging (issued >=1 phase ago) must be complete
    asm volatile("s_waitcnt lgkmcnt(0)" ::: "memory");
    asm volatile("s_waitcnt vmcnt(0)" ::: "memory");
    __builtin_amdgcn_sched_barrier(0);
    __builtin_amdgcn_s_barrier();
  }

  if (MODE == 0) {
    #pragma unroll
    for (int mi = 0; mi < 4; mi++) {
      #pragma unroll
      for (int ni = 0; ni < 4; ni++) {
        int base = n0 + wc * 64 + ni * 16;   // 16-aligned; one (which,h) per frag
        int which = base / 768;
        int hd = base - which * 768;         // h*96 + d0
        int h = hd / 96;
        int d0 = hd - h * 96;
        float bb = bias[(hd + l15) * 3 + which];  // original b_qkv index
        int rowb = m0 + wr * 64 + mi * 16 + l16 * 4;
        int bi = rowb >> 11, nnb = rowb & 2047;
        size_t bh = (size_t)(bi * NHEADS + h);
        if (which == 2) {
          // pi bit-permute (keeps low 2 bits): sigma order for attn PV frags
          int nn2 = (nnb & ~63) | (nnb & 32) | ((nnb & 12) << 1) | ((nnb & 16) >> 2) | (nnb & 3);
          float v0 = acc[mi][ni][0] + bb, v1 = acc[mi][ni][1] + bb;
          float v2 = acc[mi][ni][2] + bb, v3 = acc[mi][ni][3] + bb;
          uint2 pk;
          pk.x = cvt_pk_bf16(v0, v1);
          pk.y = cvt_pk_bf16(v2, v3);
          *(uint2*)(Vt + (bh * HDIM + d0 + l15) * SEQ + nn2) = pk;
        } else {
          #pragma unroll
          for (int j = 0; j < 4; j++) {
            float v = acc[mi][ni][j] + bb;
            int nn = nnb + j;
            if (which == 0) Qo[(bh * SEQ + nn) * HDIM + d0 + l15] = f2bf(v * QSCALE);
            else            Ko[(bh * SEQ + nn) * HDIM + d0 + l15] = f2bf(v);
          }
        }
      }
    }
  } else {
    #pragma unroll
    for (int mi = 0; mi < 4; mi++) {
      #pragma unroll
      for (int ni = 0; ni < 4; ni++) {
        int col = n0 + wc * 64 + ni * 16 + l15;
        float bb = bias[col];
        #pragma unroll
        for (int j = 0; j < 4; j++) {
          int row = m0 + wr * 64 + mi * 16 + l16 * 4 + j;
          out[(size_t)row * EMBED + col] = acc[mi][ni][j] + bb;
        }
      }
    }
  }
}

// ---------------- flash attention (swapped QK^T, P entirely in registers) ----------------
// Q [B*H][N][96] bf16 (pre-scaled), K same, Vt [B*H][96][N] bf16 with pi-permuted cols.
// Out: attn [B][N][H*96] bf16. KVBLK=64 double-buffered, 1 barrier/iter.
__global__ __launch_bounds__(256) void attn_kernel(
    const unsigned short* __restrict__ Q, const unsigned short* __restrict__ Kd,
    const unsigned short* __restrict__ Vt, unsigned short* __restrict__ Oa) {
  __shared__ unsigned short Ks[2][64 * 96];   // row-major [64][96]
  __shared__ unsigned short Vs[2][96 * 64];   // [d][sigma-k], 16B slots XOR (d&7)

  const int tid = threadIdx.x, lane = tid & 63, wid = tid >> 6;
  const int l15 = lane & 15, l16 = lane >> 4;
  const int bid = blockIdx.x;
  const int swz = (bid & 7) * 64 + (bid >> 3);
  const int qb_ = swz & 15, bh = swz >> 4;
  const int bi = bh >> 3, h = bh & 7;
  const int q0 = qb_ * 128;

  const unsigned short* Qg = Q + ((size_t)bh * SEQ + q0) * HDIM;
  const unsigned short* Kg = Kd + (size_t)bh * SEQ * HDIM;
  const unsigned short* Vg = Vt + (size_t)bh * HDIM * SEQ;

  bf16x8 qf[2][3];
  #pragma unroll
  for (int qb = 0; qb < 2; qb++)
    #pragma unroll
    for (int ks = 0; ks < 3; ks++)
      qf[qb][ks] = *(const bf16x8*)(Qg + (size_t)(wid * 32 + qb * 16 + l15) * HDIM + ks * 32 + l16 * 8);

  auto stageKV = [&](int buf, int k0) {
    #pragma unroll
    for (int i = 0; i < 3; i++) {
      int idx = i * 256 + tid;
      gload_lds16(Kg + (size_t)k0 * HDIM + idx * 8,
                  (char*)&Ks[buf][0] + (i * 256 + wid * 64) * 16);
    }
    #pragma unroll
    for (int i = 0; i < 3; i++) {
      int idx = i * 256 + tid;
      int d = idx >> 3, s = idx & 7;
      gload_lds16(Vg + (size_t)d * SEQ + k0 + ((s ^ (d & 7)) << 3),
                  (char*)&Vs[buf][0] + (i * 256 + wid * 64) * 16);
    }
  };

  f32x4 oacc[2][6] = {};
  float mrow[2], lrow[2];
  mrow[0] = mrow[1] = -__builtin_inff();
  lrow[0] = lrow[1] = 0.f;

  stageKV(0, 0);
  __syncthreads();

  for (int kb = 0; kb < SEQ / 64; kb++) {
    const int cur = kb & 1;
    if (kb + 1 < SEQ / 64) stageKV(cur ^ 1, (kb + 1) * 64);

    const char* Kc = (const char*)&Ks[cur][0];
    const char* Vc = (const char*)&Vs[cur][0];

    f32x4 sacc[2][4] = {};
    #pragma unroll
    for (int ks = 0; ks < 3; ks++) {
      bf16x8 ak[4];
      #pragma unroll
      for (int ni = 0; ni < 4; ni++)
        ak[ni] = *(const bf16x8*)(Kc + (ni * 16 + l15) * 192 + ks * 64 + l16 * 16);
      #pragma unroll
      for (int qb = 0; qb < 2; qb++)
        #pragma unroll
        for (int ni = 0; ni < 4; ni++)
          sacc[qb][ni] = __builtin_amdgcn_mfma_f32_16x16x32_bf16(ak[ni], qf[qb][ks], sacc[qb][ni], 0, 0, 0);
    }

    float tmax[2];
    float g = -3.4e38f;
    #pragma unroll
    for (int qb = 0; qb < 2; qb++) {
      float a0 = fmaxf(fmaxf(sacc[qb][0][0], sacc[qb][0][1]), fmaxf(sacc[qb][0][2], sacc[qb][0][3]));
      float a1 = fmaxf(fmaxf(sacc[qb][1][0], sacc[qb][1][1]), fmaxf(sacc[qb][1][2], sacc[qb][1][3]));
      float a2 = fmaxf(fmaxf(sacc[qb][2][0], sacc[qb][2][1]), fmaxf(sacc[qb][2][2], sacc[qb][2][3]));
      float a3 = fmaxf(fmaxf(sacc[qb][3][0], sacc[qb][3][1]), fmaxf(sacc[qb][3][2], sacc[qb][3][3]));
      float v = fmaxf(fmaxf(a0, a1), fmaxf(a2, a3));
      v = fmaxf(v, __shfl_xor(v, 16));
      v = fmaxf(v, __shfl_xor(v, 32));
      tmax[qb] = v;
      g = fmaxf(g, v - mrow[qb]);
    }
    if (!__all(g <= 11.54f)) {
      #pragma unroll
      for (int qb = 0; qb < 2; qb++) {
        float mnew = fmaxf(mrow[qb], tmax[qb]);
        float alpha = __builtin_amdgcn_exp2f(mrow[qb] - mnew);
        mrow[qb] = mnew;
        lrow[qb] *= alpha;
        #pragma unroll
        for (int d6 = 0; d6 < 6; d6++) {
          oacc[qb][d6][0] *= alpha; oacc[qb][d6][1] *= alpha;
          oacc[qb][d6][2] *= alpha; oacc[qb][d6][3] *= alpha;
        }
      }
    }

    unsigned int pk[2][8];
    #pragma unroll
    for (int qb = 0; qb < 2; qb++) {
      const float m = mrow[qb];
      float psum = 0.f;
      #pragma unroll
      for (int ni = 0; ni < 4; ni++) {
        float p0 = __builtin_amdgcn_exp2f(sacc[qb][ni][0] - m);
        float p1 = __builtin_amdgcn_exp2f(sacc[qb][ni][1] - m);
        float p2 = __builtin_amdgcn_exp2f(sacc[qb][ni][2] - m);
        float p3 = __builtin_amdgcn_exp2f(sacc[qb][ni][3] - m);
        psum += (p0 + p1) + (p2 + p3);
        pk[qb][ni * 2]     = cvt_pk_bf16(p0, p1);
        pk[qb][ni * 2 + 1] = cvt_pk_bf16(p2, p3);
      }
      psum += __shfl_xor(psum, 16);
      psum += __shfl_xor(psum, 32);
      lrow[qb] += psum;
    }

    #pragma unroll
    for (int ks = 0; ks < 2; ks++) {
      bf16x8 vb[6];
      #pragma unroll
      for (int d6 = 0; d6 < 6; d6++)
        vb[d6] = *(const bf16x8*)(Vc + (d6 * 16 + l15) * 128 +
                                  (((ks * 4 + l16) ^ (l15 & 7)) << 4));
      #pragma unroll
      for (int qb = 0; qb < 2; qb++) {
        union { unsigned int u[4]; bf16x8 v; } pf;
        pf.u[0] = pk[qb][4 * ks];     pf.u[1] = pk[qb][4 * ks + 1];
        pf.u[2] = pk[qb][4 * ks + 2]; pf.u[3] = pk[qb][4 * ks + 3];
        #pragma unroll
        for (int d6 = 0; d6 < 6; d6++)
          oacc[qb][d6] = __builtin_amdgcn_mfma_f32_16x16x32_bf16(vb[d6], pf.v, oacc[qb][d6], 0, 0, 0);
      }
    }

    __syncthreads();
  }

  #pragma unroll
  for (int qb = 0; qb < 2; qb++) {
    const float rl = 1.f / lrow[qb];
    const int tok = q0 + wid * 32 + qb * 16 + l15;
    unsigned short* Og = Oa + ((size_t)bi * SEQ + tok) * EMBED + h * HDIM;
    #pragma unroll
    for (int d6 = 0; d6 < 6; d6++) {
      uint2 o;
      o.x = cvt_pk_bf16(oacc[qb][d6][0] * rl, oacc[qb][d6][1] * rl);
      o.y = cvt_pk_bf16(oacc[qb][d6][2] * rl, oacc[qb][d6][3] * rl);
      *(uint2*)(Og + d6 * 16 + l16 * 4) = o;
    }
  }
}

extern "C" void kernel_launch(void* const* d_in, const int* in_sizes, int n_in,
                              void* d_out, int out_size, void* d_ws, size_t ws_size,
                              hipStream_t stream) {
  const float* x      = (const float*)d_in[0];
  const float* W_qkv  = (const float*)d_in[1];
  const float* b_qkv  = (const float*)d_in[2];
  const float* W_proj = (const float*)d_in[3];
  const float* b_proj = (const float*)d_in[4];
  float* out = (float*)d_out;

  char* ws = (char*)d_ws;
  size_t off = 0;
  auto alloc = [&](size_t bytes) { void* p = ws + off; off += (bytes + 255) & ~(size_t)255; return p; };
  unsigned short* xb  = (unsigned short*)alloc((size_t)NTOK * EMBED * 2);
  unsigned short* WqT = (unsigned short*)alloc((size_t)QKVN * EMBED * 2);
  unsigned short* WpT = (unsigned short*)alloc((size_t)EMBED * EMBED * 2);
  unsigned short* Qb  = (unsigned short*)alloc((size_t)NTOK * EMBED * 2);
  unsigned short* Kb  = (unsigned short*)alloc((size_t)NTOK * EMBED * 2);
  unsigned short* Vtb = (unsigned short*)alloc((size_t)NTOK * EMBED * 2);
  unsigned short* Ob  = (unsigned short*)alloc((size_t)NTOK * EMBED * 2);

  cast_x_kernel<<<dim3(NTOK * EMBED / 4 / 256), dim3(256), 0, stream>>>(
      (const float4*)x, (ushort4*)xb, NTOK * EMBED / 4);
  transpose_cast_kernel<<<dim3(QKVN / 32, EMBED / 32), dim3(256), 0, stream>>>(W_qkv, WqT, EMBED, QKVN, 1);
  transpose_cast_kernel<<<dim3(EMBED / 32, EMBED / 32), dim3(256), 0, stream>>>(W_proj, WpT, EMBED, EMBED, 0);

  // qkv: M=8192, N=2304 -> grid 64*18 = 1152 (multiple of 8)
  gemm8_kernel<0><<<dim3((NTOK / 128) * (QKVN / 128)), dim3(256), 0, stream>>>(
      xb, WqT, b_qkv, EMBED, QKVN / 128, Qb, Kb, Vtb, nullptr);

  attn_kernel<<<dim3(BATCH * NHEADS * (SEQ / 128)), dim3(256), 0, stream>>>(Qb, Kb, Vtb, Ob);

  // proj: M=8192, N=768 -> grid 64*6 = 384 (multiple of 8)
  gemm8_kernel<1><<<dim3((NTOK / 128) * (EMBED / 128)), dim3(256), 0, stream>>>(
      Ob, WpT, b_proj, EMBED, EMBED / 128, nullptr, nullptr, nullptr, out);
}